// Round 10
// baseline (719.995 us; speedup 1.0000x reference)
//
#include <hip/hip_runtime.h>

#define BLOCK 256
#define IC    64           // staged points per chunk
#define RPT   2            // rows per thread
#define ROWS  (BLOCK*RPT)  // 512 rows per block
#define RBLK  64

__device__ __forceinline__ float wave_reduce_add(float v) {
#pragma unroll
    for (int off = 32; off > 0; off >>= 1) v += __shfl_down(v, off, 64);
    return v;
}
__device__ __forceinline__ float lg2(float x) { return __builtin_amdgcn_logf(x); }
__device__ __forceinline__ float ex2(float x) { return __builtin_amdgcn_exp2f(x); }

// 2 rows = 6 floats at 8-byte-aligned offset -> three float2 loads
__device__ __forceinline__ void load_rows(const float* p, float* x, float* y, float* z) {
    float2 v0 = *(const float2*)p;
    float2 v1 = *(const float2*)(p + 2);
    float2 v2 = *(const float2*)(p + 4);
    x[0]=v0.x; y[0]=v0.y; z[0]=v1.x;
    x[1]=v1.y; y[1]=v2.x; z[1]=v2.y;
}

__global__ __launch_bounds__(BLOCK)
void emd_init(float* __restrict__ satl, float* __restrict__ satr,
              float* __restrict__ out, float fl, float fr,
              int b, int n, int m) {
    int idx = blockIdx.x * blockDim.x + threadIdx.x;
    if (idx < b * n) satl[idx] = fl;
    if (idx < b * m) satr[idx] = fr;
    if (idx < b)     out[idx]  = 0.f;
}

// ---------- level-0 rowsum1 ----------
__global__ __launch_bounds__(BLOCK, 8)
void emd_pass1(const float* __restrict__ xyz1, const float* __restrict__ xyz2,
               float* __restrict__ P1p, float ls, float wconst, float thr,
               int n, int m, int bn)
{
    __shared__ float4 sh[IC];
    const int bb = blockIdx.z, chunk = blockIdx.y;

    const int i0 = blockIdx.x * ROWS + threadIdx.x * RPT;
    float x[RPT], y[RPT], z[RPT], acc[RPT];
    load_rows(xyz1 + ((size_t)bb * n + i0) * 3, x, y, z);

    const float* x2 = xyz2 + (size_t)bb * m * 3;
    for (int t = threadIdx.x; t < IC; t += BLOCK) {
        int j = chunk * IC + t;
        sh[t] = make_float4(x2[3*j], x2[3*j+1], x2[3*j+2], wconst);
    }
    __syncthreads();

#pragma unroll
    for (int r = 0; r < RPT; ++r) acc[r] = 0.f;
#pragma unroll 2
    for (int tb = 0; tb < IC; tb += 4) {
        float4 q0 = sh[tb+0], q1 = sh[tb+1], q2 = sh[tb+2], q3 = sh[tb+3];
        float d0[RPT], d1[RPT], d2v[RPT], d3[RPT];
        float dmin = 1e30f;
#pragma unroll
        for (int r = 0; r < RPT; ++r) {
            float dx, dy, dz;
            dx=x[r]-q0.x; dy=y[r]-q0.y; dz=z[r]-q0.z; d0[r]=fmaf(dz,dz,fmaf(dy,dy,dx*dx));
            dx=x[r]-q1.x; dy=y[r]-q1.y; dz=z[r]-q1.z; d1[r]=fmaf(dz,dz,fmaf(dy,dy,dx*dx));
            dx=x[r]-q2.x; dy=y[r]-q2.y; dz=z[r]-q2.z; d2v[r]=fmaf(dz,dz,fmaf(dy,dy,dx*dx));
            dx=x[r]-q3.x; dy=y[r]-q3.y; dz=z[r]-q3.z; d3[r]=fmaf(dz,dz,fmaf(dy,dy,dx*dx));
            dmin = fminf(dmin, fminf(fminf(d0[r], d1[r]), fminf(d2v[r], d3[r])));
        }
        if (__any(dmin < thr)) {
#pragma unroll
            for (int r = 0; r < RPT; ++r) {
                acc[r] += ex2(fmaf(d0[r],  ls, q0.w));
                acc[r] += ex2(fmaf(d1[r],  ls, q1.w));
                acc[r] += ex2(fmaf(d2v[r], ls, q2.w));
                acc[r] += ex2(fmaf(d3[r],  ls, q3.w));
            }
        }
    }
    float* dst = &P1p[(size_t)chunk * bn + (size_t)bb * n + i0];
    *(float2*)dst = make_float2(acc[0], acc[1]);
}

// ---------- pass2 (+fused redL) ----------
__global__ __launch_bounds__(BLOCK, 8)
void emd_pass2(const float* __restrict__ xyzO, const float* __restrict__ xyzS,
               const float* __restrict__ satlIn, float* __restrict__ satlOut,
               const float* __restrict__ aIn, float* __restrict__ aOut,
               const float* __restrict__ P1p, const float* __restrict__ P3a,
               const float* __restrict__ P3b, float* __restrict__ P2p,
               float* __restrict__ cost,
               float ls, float thr, int nO, int nS, int bnS, int bnO,
               int C4, int first)
{
    __shared__ float4 sh[IC];
    __shared__ float red[3][4][IC];
    const int bb = blockIdx.z, chunk = blockIdx.y;

    const int j0 = blockIdx.x * ROWS + threadIdx.x * RPT;
    float x[RPT], y[RPT], z[RPT], acc[RPT];
    load_rows(xyzO + ((size_t)bb * nO + j0) * 3, x, y, z);

    const int t6 = threadIdx.x & 63, g = threadIdx.x >> 6;
    const size_t ri = (size_t)bb * nS + chunk * IC + t6;
    {
        float ps = 0.f, pa = 0.f, pb = 0.f;
        const int c0 = g * C4;
        if (first) {
#pragma unroll 16
            for (int k = 0; k < C4; ++k) ps += P1p[(size_t)(c0 + k) * bnS + ri];
        } else {
#pragma unroll 16
            for (int k = 0; k < C4; ++k) {
                ps += P1p[(size_t)(c0 + k) * bnS + ri];
                pa += P3a[(size_t)(c0 + k) * bnS + ri];
                pb += P3b[(size_t)(c0 + k) * bnS + ri];
            }
        }
        red[0][g][t6] = ps; red[1][g][t6] = pa; red[2][g][t6] = pb;
    }
    __syncthreads();
    if (threadIdx.x < IC) {
        float rs = red[0][0][t6] + red[0][1][t6] + red[0][2][t6] + red[0][3][t6];
        float sl, costv = 0.f;
        if (first) {
            sl = satlIn[ri];
        } else {
            float s1 = red[1][0][t6] + red[1][1][t6] + red[1][2][t6] + red[1][3][t6];
            float s2 = red[2][0][t6] + red[2][1][t6] + red[2][2][t6] + red[2][3][t6];
            float ap = aIn[ri];
            sl = fmaxf(satlIn[ri] - ap * s1, 0.f);
            costv = ap * s2;
        }
        float av = sl / (rs + 1e-9f);
        if (blockIdx.x == 0) {
            satlOut[ri] = sl;
            aOut[ri]    = av;
            if (!first) {
                float cv = wave_reduce_add(costv);
                if (t6 == 0) atomicAdd(&cost[bb], cv);
            }
        }
        const float* xs = xyzS + ((size_t)bb * nS + chunk * IC + t6) * 3;
        sh[t6] = make_float4(xs[0], xs[1], xs[2], lg2(av));
    }
    __syncthreads();

#pragma unroll
    for (int r = 0; r < RPT; ++r) acc[r] = 0.f;
    if (thr < 1e29f) {
#pragma unroll 2
        for (int tb = 0; tb < IC; tb += 4) {
            float4 q0 = sh[tb+0], q1 = sh[tb+1], q2 = sh[tb+2], q3 = sh[tb+3];
            float d0[RPT], d1[RPT], d2v[RPT], d3[RPT];
            float dmin = 1e30f;
#pragma unroll
            for (int r = 0; r < RPT; ++r) {
                float dx, dy, dz;
                dx=x[r]-q0.x; dy=y[r]-q0.y; dz=z[r]-q0.z; d0[r]=fmaf(dz,dz,fmaf(dy,dy,dx*dx));
                dx=x[r]-q1.x; dy=y[r]-q1.y; dz=z[r]-q1.z; d1[r]=fmaf(dz,dz,fmaf(dy,dy,dx*dx));
                dx=x[r]-q2.x; dy=y[r]-q2.y; dz=z[r]-q2.z; d2v[r]=fmaf(dz,dz,fmaf(dy,dy,dx*dx));
                dx=x[r]-q3.x; dy=y[r]-q3.y; dz=z[r]-q3.z; d3[r]=fmaf(dz,dz,fmaf(dy,dy,dx*dx));
                dmin = fminf(dmin, fminf(fminf(d0[r], d1[r]), fminf(d2v[r], d3[r])));
            }
            if (__any(dmin < thr)) {
#pragma unroll
                for (int r = 0; r < RPT; ++r) {
                    acc[r] += ex2(fmaf(d0[r],  ls, q0.w));
                    acc[r] += ex2(fmaf(d1[r],  ls, q1.w));
                    acc[r] += ex2(fmaf(d2v[r], ls, q2.w));
                    acc[r] += ex2(fmaf(d3[r],  ls, q3.w));
                }
            }
        }
    } else {
#pragma unroll 2
        for (int tb = 0; tb < IC; tb += 4) {
            float4 q0 = sh[tb+0], q1 = sh[tb+1], q2 = sh[tb+2], q3 = sh[tb+3];
#pragma unroll
            for (int r = 0; r < RPT; ++r) {
                float dx, dy, dz, d2;
                dx=x[r]-q0.x; dy=y[r]-q0.y; dz=z[r]-q0.z;
                d2=fmaf(dz,dz,fmaf(dy,dy,dx*dx)); acc[r] += ex2(fmaf(d2, ls, q0.w));
                dx=x[r]-q1.x; dy=y[r]-q1.y; dz=z[r]-q1.z;
                d2=fmaf(dz,dz,fmaf(dy,dy,dx*dx)); acc[r] += ex2(fmaf(d2, ls, q1.w));
                dx=x[r]-q2.x; dy=y[r]-q2.y; dz=z[r]-q2.z;
                d2=fmaf(dz,dz,fmaf(dy,dy,dx*dx)); acc[r] += ex2(fmaf(d2, ls, q2.w));
                dx=x[r]-q3.x; dy=y[r]-q3.y; dz=z[r]-q3.z;
                d2=fmaf(dz,dz,fmaf(dy,dy,dx*dx)); acc[r] += ex2(fmaf(d2, ls, q3.w));
            }
        }
    }
    float* dst = &P2p[(size_t)chunk * bnO + (size_t)bb * nO + j0];
    *(float2*)dst = make_float2(acc[0], acc[1]);
}

// ---------- fused (+redR) ----------
__global__ __launch_bounds__(BLOCK, 8)
void emd_fused(const float* __restrict__ xyz1, const float* __restrict__ xyz2,
               const float* __restrict__ satrIn, float* __restrict__ satrOut,
               const float* __restrict__ P2p,
               float* __restrict__ P3a, float* __restrict__ P3b,
               float* __restrict__ P1p,
               float lsA, float lsB, float thr,
               int n, int m, int bn, int bm, int C4, int sumOnly)
{
    __shared__ float4 sh[IC];
    __shared__ float  shB[IC];
    __shared__ float  red[4][IC];
    __shared__ float  snsumS;
    const int bb = blockIdx.z, chunk = blockIdx.y;

    const int i0 = blockIdx.x * ROWS + threadIdx.x * RPT;
    float x[RPT], y[RPT], z[RPT];
    load_rows(xyz1 + ((size_t)bb * n + i0) * 3, x, y, z);

    const int t6 = threadIdx.x & 63, g = threadIdx.x >> 6;
    const size_t rj = (size_t)bb * m + chunk * IC + t6;
    {
        float ps = 0.f;
        const int c0 = g * C4;
#pragma unroll 16
        for (int k = 0; k < C4; ++k) ps += P2p[(size_t)(c0 + k) * bm + rj];
        red[g][t6] = ps;
    }
    __syncthreads();
    if (threadIdx.x < IC) {
        float cs  = red[0][t6] + red[1][t6] + red[2][t6] + red[3][t6];
        float sr  = satrIn[rj];
        float cs2 = sr * cs;
        float inv = sr / (cs2 + 1e-9f);
        float r2  = sr * inv;
        float sn  = fmaxf(sr - cs2 * inv, 0.f);
        if (blockIdx.x == 0) satrOut[rj] = sn;
        const float* xs = xyz2 + ((size_t)bb * m + chunk * IC + t6) * 3;
        sh[t6]  = make_float4(xs[0], xs[1], xs[2], lg2(r2));
        shB[t6] = lg2(sn);
        if (sumOnly) {
            float ss = wave_reduce_add(sn);
            if (t6 == 0) snsumS = ss;
        }
    }
    __syncthreads();

    float s1[RPT], s2[RPT], r1[RPT];
#pragma unroll
    for (int r = 0; r < RPT; ++r) { s1[r] = 0.f; s2[r] = 0.f; r1[r] = 0.f; }

    if (thr < 1e29f) {
#pragma unroll 2
        for (int tb = 0; tb < IC; tb += 4) {
            float4 q0 = sh[tb+0], q1 = sh[tb+1], q2 = sh[tb+2], q3 = sh[tb+3];
            float lb0 = shB[tb+0], lb1 = shB[tb+1], lb2 = shB[tb+2], lb3 = shB[tb+3];
            float d0[RPT], d1[RPT], d2v[RPT], d3[RPT];
            float dmin = 1e30f;
#pragma unroll
            for (int r = 0; r < RPT; ++r) {
                float dx, dy, dz;
                dx=x[r]-q0.x; dy=y[r]-q0.y; dz=z[r]-q0.z; d0[r]=fmaf(dz,dz,fmaf(dy,dy,dx*dx));
                dx=x[r]-q1.x; dy=y[r]-q1.y; dz=z[r]-q1.z; d1[r]=fmaf(dz,dz,fmaf(dy,dy,dx*dx));
                dx=x[r]-q2.x; dy=y[r]-q2.y; dz=z[r]-q2.z; d2v[r]=fmaf(dz,dz,fmaf(dy,dy,dx*dx));
                dx=x[r]-q3.x; dy=y[r]-q3.y; dz=z[r]-q3.z; d3[r]=fmaf(dz,dz,fmaf(dy,dy,dx*dx));
                dmin = fminf(dmin, fminf(fminf(d0[r], d1[r]), fminf(d2v[r], d3[r])));
            }
            if (__any(dmin < thr)) {
#pragma unroll
                for (int r = 0; r < RPT; ++r) {
                    float e;
                    e = ex2(fmaf(d0[r], lsA, q0.w));
                    s1[r] += e; s2[r] = fmaf(e, __builtin_amdgcn_sqrtf(d0[r]), s2[r]);
                    r1[r] += ex2(fmaf(d0[r], lsB, lb0));
                    e = ex2(fmaf(d1[r], lsA, q1.w));
                    s1[r] += e; s2[r] = fmaf(e, __builtin_amdgcn_sqrtf(d1[r]), s2[r]);
                    r1[r] += ex2(fmaf(d1[r], lsB, lb1));
                    e = ex2(fmaf(d2v[r], lsA, q2.w));
                    s1[r] += e; s2[r] = fmaf(e, __builtin_amdgcn_sqrtf(d2v[r]), s2[r]);
                    r1[r] += ex2(fmaf(d2v[r], lsB, lb2));
                    e = ex2(fmaf(d3[r], lsA, q3.w));
                    s1[r] += e; s2[r] = fmaf(e, __builtin_amdgcn_sqrtf(d3[r]), s2[r]);
                    r1[r] += ex2(fmaf(d3[r], lsB, lb3));
                }
            }
        }
    } else if (sumOnly) {
#pragma unroll 2
        for (int tb = 0; tb < IC; tb += 4) {
            float4 q0 = sh[tb+0], q1 = sh[tb+1], q2 = sh[tb+2], q3 = sh[tb+3];
#pragma unroll
            for (int r = 0; r < RPT; ++r) {
                float dx, dy, dz, d2, e;
                dx=x[r]-q0.x; dy=y[r]-q0.y; dz=z[r]-q0.z;
                d2=fmaf(dz,dz,fmaf(dy,dy,dx*dx));
                e = ex2(fmaf(d2, lsA, q0.w));
                s1[r] += e; s2[r] = fmaf(e, __builtin_amdgcn_sqrtf(d2), s2[r]);
                dx=x[r]-q1.x; dy=y[r]-q1.y; dz=z[r]-q1.z;
                d2=fmaf(dz,dz,fmaf(dy,dy,dx*dx));
                e = ex2(fmaf(d2, lsA, q1.w));
                s1[r] += e; s2[r] = fmaf(e, __builtin_amdgcn_sqrtf(d2), s2[r]);
                dx=x[r]-q2.x; dy=y[r]-q2.y; dz=z[r]-q2.z;
                d2=fmaf(dz,dz,fmaf(dy,dy,dx*dx));
                e = ex2(fmaf(d2, lsA, q2.w));
                s1[r] += e; s2[r] = fmaf(e, __builtin_amdgcn_sqrtf(d2), s2[r]);
                dx=x[r]-q3.x; dy=y[r]-q3.y; dz=z[r]-q3.z;
                d2=fmaf(dz,dz,fmaf(dy,dy,dx*dx));
                e = ex2(fmaf(d2, lsA, q3.w));
                s1[r] += e; s2[r] = fmaf(e, __builtin_amdgcn_sqrtf(d2), s2[r]);
            }
        }
    } else {
#pragma unroll 2
        for (int tb = 0; tb < IC; tb += 4) {
            float4 q0 = sh[tb+0], q1 = sh[tb+1], q2 = sh[tb+2], q3 = sh[tb+3];
            float lb0 = shB[tb+0], lb1 = shB[tb+1], lb2 = shB[tb+2], lb3 = shB[tb+3];
#pragma unroll
            for (int r = 0; r < RPT; ++r) {
                float dx, dy, dz, d2, e;
                dx=x[r]-q0.x; dy=y[r]-q0.y; dz=z[r]-q0.z;
                d2=fmaf(dz,dz,fmaf(dy,dy,dx*dx));
                e = ex2(fmaf(d2, lsA, q0.w));
                s1[r] += e; s2[r] = fmaf(e, __builtin_amdgcn_sqrtf(d2), s2[r]);
                r1[r] += ex2(fmaf(d2, lsB, lb0));
                dx=x[r]-q1.x; dy=y[r]-q1.y; dz=z[r]-q1.z;
                d2=fmaf(dz,dz,fmaf(dy,dy,dx*dx));
                e = ex2(fmaf(d2, lsA, q1.w));
                s1[r] += e; s2[r] = fmaf(e, __builtin_amdgcn_sqrtf(d2), s2[r]);
                r1[r] += ex2(fmaf(d2, lsB, lb1));
                dx=x[r]-q2.x; dy=y[r]-q2.y; dz=z[r]-q2.z;
                d2=fmaf(dz,dz,fmaf(dy,dy,dx*dx));
                e = ex2(fmaf(d2, lsA, q2.w));
                s1[r] += e; s2[r] = fmaf(e, __builtin_amdgcn_sqrtf(d2), s2[r]);
                r1[r] += ex2(fmaf(d2, lsB, lb2));
                dx=x[r]-q3.x; dy=y[r]-q3.y; dz=z[r]-q3.z;
                d2=fmaf(dz,dz,fmaf(dy,dy,dx*dx));
                e = ex2(fmaf(d2, lsA, q3.w));
                s1[r] += e; s2[r] = fmaf(e, __builtin_amdgcn_sqrtf(d2), s2[r]);
                r1[r] += ex2(fmaf(d2, lsB, lb3));
            }
        }
    }
    size_t base = (size_t)chunk * bn + (size_t)bb * n + i0;
    if (sumOnly) {
        float sc = snsumS;
#pragma unroll
        for (int r = 0; r < RPT; ++r) r1[r] = sc;
    }
    *(float2*)&P3a[base] = make_float2(s1[0], s1[1]);
    *(float2*)&P3b[base] = make_float2(s2[0], s2[1]);
    *(float2*)&P1p[base] = make_float2(r1[0], r1[1]);
}

// ---------- last level (+redR linear) ----------
__global__ __launch_bounds__(BLOCK, 8)
void emd_pass3_last(const float* __restrict__ xyz1, const float* __restrict__ xyz2,
                    const float* __restrict__ satrIn, const float* __restrict__ P2p,
                    float* __restrict__ P3b, int n, int m, int bn, int bm, int C4)
{
    __shared__ float4 sh[IC];
    __shared__ float red[4][IC];
    const int bb = blockIdx.z, chunk = blockIdx.y;

    const int i0 = blockIdx.x * ROWS + threadIdx.x * RPT;
    float x[RPT], y[RPT], z[RPT], s2[RPT];
    load_rows(xyz1 + ((size_t)bb * n + i0) * 3, x, y, z);

    const int t6 = threadIdx.x & 63, g = threadIdx.x >> 6;
    const size_t rj = (size_t)bb * m + chunk * IC + t6;
    {
        float ps = 0.f;
        const int c0 = g * C4;
#pragma unroll 16
        for (int k = 0; k < C4; ++k) ps += P2p[(size_t)(c0 + k) * bm + rj];
        red[g][t6] = ps;
    }
    __syncthreads();
    if (threadIdx.x < IC) {
        float cs  = red[0][t6] + red[1][t6] + red[2][t6] + red[3][t6];
        float sr  = satrIn[rj];
        float cs2 = sr * cs;
        float inv = sr / (cs2 + 1e-9f);
        const float* xs = xyz2 + ((size_t)bb * m + chunk * IC + t6) * 3;
        sh[t6] = make_float4(xs[0], xs[1], xs[2], sr * inv);
    }
    __syncthreads();

#pragma unroll
    for (int r = 0; r < RPT; ++r) s2[r] = 0.f;
#pragma unroll 4
    for (int tb = 0; tb < IC; tb += 4) {
        float4 q0 = sh[tb+0], q1 = sh[tb+1], q2 = sh[tb+2], q3 = sh[tb+3];
#pragma unroll
        for (int r = 0; r < RPT; ++r) {
            float dx, dy, dz, d2;
            dx = x[r]-q0.x; dy = y[r]-q0.y; dz = z[r]-q0.z;
            d2 = fmaf(dz, dz, fmaf(dy, dy, dx*dx));
            s2[r] = fmaf(q0.w, __builtin_amdgcn_sqrtf(d2), s2[r]);
            dx = x[r]-q1.x; dy = y[r]-q1.y; dz = z[r]-q1.z;
            d2 = fmaf(dz, dz, fmaf(dy, dy, dx*dx));
            s2[r] = fmaf(q1.w, __builtin_amdgcn_sqrtf(d2), s2[r]);
            dx = x[r]-q2.x; dy = y[r]-q2.y; dz = z[r]-q2.z;
            d2 = fmaf(dz, dz, fmaf(dy, dy, dx*dx));
            s2[r] = fmaf(q2.w, __builtin_amdgcn_sqrtf(d2), s2[r]);
            dx = x[r]-q3.x; dy = y[r]-q3.y; dz = z[r]-q3.z;
            d2 = fmaf(dz, dz, fmaf(dy, dy, dx*dx));
            s2[r] = fmaf(q3.w, __builtin_amdgcn_sqrtf(d2), s2[r]);
        }
    }
    *(float2*)&P3b[(size_t)chunk * bn + (size_t)bb * n + i0] =
        make_float2(s2[0], s2[1]);
}

__global__ __launch_bounds__(RBLK)
void emd_final(const float* __restrict__ a, const float* __restrict__ P3b,
               float* __restrict__ cost, int C, int bn, int n)
{
    const int idx = blockIdx.x * RBLK + threadIdx.x;
    float s2 = 0.f;
#pragma unroll 16
    for (int c = 0; c < C; ++c) s2 += P3b[(size_t)c * bn + idx];
    float cv = wave_reduce_add(a[idx] * s2);
    if (threadIdx.x == 0) atomicAdd(&cost[idx / n], cv);
}

extern "C" void kernel_launch(void* const* d_in, const int* in_sizes, int n_in,
                              void* d_out, int out_size, void* d_ws, size_t ws_size,
                              hipStream_t stream)
{
    const float* xyz1 = (const float*)d_in[0];
    const float* xyz2 = (const float*)d_in[1];
    const int b = out_size;                 // 4
    const int n = in_sizes[0] / (3 * b);    // 4096
    const int m = in_sizes[1] / (3 * b);    // 4096
    const int C  = m / IC;                  // j-chunk count
    const int C2 = n / IC;                  // i-chunk count
    const int bn = b * n, bm = b * m;

    float* ws    = (float*)d_ws;
    float* satlA = ws; ws += (size_t)bn;
    float* satlB = ws; ws += (size_t)bn;
    float* satrA = ws; ws += (size_t)bm;
    float* satrB = ws; ws += (size_t)bm;
    float* aA    = ws; ws += (size_t)bn;
    float* aB    = ws; ws += (size_t)bn;
    float* P1p   = ws; ws += (size_t)bn * C;
    float* P2p   = ws; ws += (size_t)bm * C2;
    float* P3a   = ws; ws += (size_t)bn * C;
    float* P3b   = ws; ws += (size_t)bn * C;

    float* out = (float*)d_out;

    const int mx = n > m ? n : m;
    const float fl = (float)(mx / n), fr = (float)(mx / m);
    const float lgfr = log2f(fr);

    emd_init<<<dim3((b * mx + BLOCK - 1) / BLOCK), BLOCK, 0, stream>>>(
        satlA, satrA, out, fl, fr, b, n, m);

    const double LOG2E = 1.4426950408889634074;
    const double levels[11] = {-65536.0, -16384.0, -4096.0, -1024.0, -256.0,
                               -64.0, -16.0, -4.0, -1.0, -0.25, 0.0};
    float lsv[11], thrP[11], thrF[10];
    for (int k = 0; k < 11; ++k) {
        lsv[k] = (float)(levels[k] * LOG2E);
        thrP[k] = (k <= 3) ? 165.f / fabsf(lsv[k]) : 1e30f;
    }
    for (int k = 0; k < 10; ++k)
        thrF[k] = (k <= 3) ? 165.f / fabsf(lsv[k]) : 1e30f;

    const dim3 g1(n / ROWS, m / IC, b);   // 8 x 64 x 4 = 2048 blocks
    const dim3 g2(m / ROWS, n / IC, b);
    const dim3 gRn(bn / RBLK);

    emd_pass1<<<g1, BLOCK, 0, stream>>>(xyz1, xyz2, P1p, lsv[0], lgfr, thrP[0],
                                        n, m, bn);

    float *slI = satlA, *slO = satlB, *aI = aA, *aO = aB;
    float *srI = satrA, *srO = satrB;
    for (int L = 0; L <= 10; ++L) {
        emd_pass2<<<g2, BLOCK, 0, stream>>>(xyz2, xyz1, slI, slO, aI, aO,
                                            P1p, P3a, P3b, P2p, out,
                                            lsv[L], thrP[L], m, n, bn, bm,
                                            C / 4, (L == 0) ? 1 : 0);
        { float* t = slI; slI = slO; slO = t; }
        { float* t = aI;  aI  = aO;  aO  = t; }
        if (L < 10) {
            emd_fused<<<g1, BLOCK, 0, stream>>>(xyz1, xyz2, srI, srO, P2p,
                                                P3a, P3b, P1p,
                                                lsv[L], lsv[L + 1], thrF[L],
                                                n, m, bn, bm, C2 / 4,
                                                (levels[L + 1] == 0.0) ? 1 : 0);
            { float* t = srI; srI = srO; srO = t; }
        } else {
            emd_pass3_last<<<g1, BLOCK, 0, stream>>>(xyz1, xyz2, srI, P2p, P3b,
                                                     n, m, bn, bm, C2 / 4);
        }
    }
    emd_final<<<gRn, RBLK, 0, stream>>>(aI, P3b, out, C, bn, n);
}

// Round 11
// 686.236 us; speedup vs baseline: 1.0492x; 1.0492x over previous
//
#include <hip/hip_runtime.h>

#define BLOCK 256
#define IC    64           // staged points per chunk
#define RPT   4            // rows per thread
#define ROWS  (BLOCK*RPT)  // 1024 rows per block
#define RBLK  64

__device__ __forceinline__ float wave_reduce_add(float v) {
#pragma unroll
    for (int off = 32; off > 0; off >>= 1) v += __shfl_down(v, off, 64);
    return v;
}
__device__ __forceinline__ float lg2(float x) { return __builtin_amdgcn_logf(x); }
__device__ __forceinline__ float ex2(float x) { return __builtin_amdgcn_exp2f(x); }

__device__ __forceinline__ void load_rows(const float* p, float* x, float* y, float* z) {
    float4 v0 = *(const float4*)p;
    float4 v1 = *(const float4*)(p + 4);
    float4 v2 = *(const float4*)(p + 8);
    x[0]=v0.x; x[1]=v0.w; x[2]=v1.z; x[3]=v2.y;
    y[0]=v0.y; y[1]=v1.x; y[2]=v1.w; y[3]=v2.z;
    z[0]=v0.z; z[1]=v1.y; z[2]=v2.x; z[3]=v2.w;
}

__global__ __launch_bounds__(BLOCK)
void emd_init(float* __restrict__ satl, float* __restrict__ satr,
              float* __restrict__ out, float* __restrict__ Asum,
              float fl, float fr, int b, int n, int m) {
    int idx = blockIdx.x * blockDim.x + threadIdx.x;
    if (idx < b * n) satl[idx] = fl;
    if (idx < b * m) satr[idx] = fr;
    if (idx < b)   { out[idx] = 0.f; Asum[idx] = 0.f; }
}

// ---------- level-0 rowsum1 (voted; nearly all tiles skip) ----------
__global__ __launch_bounds__(BLOCK, 4)
void emd_pass1(const float* __restrict__ xyz1, const float* __restrict__ xyz2,
               float* __restrict__ P1p, float ls, float wconst, float thr,
               int n, int m, int bn)
{
    __shared__ float4 sh[IC];
    const int bb = blockIdx.z, chunk = blockIdx.y;

    const int i0 = blockIdx.x * ROWS + threadIdx.x * RPT;
    float x[RPT], y[RPT], z[RPT], acc[RPT];
    load_rows(xyz1 + ((size_t)bb * n + i0) * 3, x, y, z);

    const float* x2 = xyz2 + (size_t)bb * m * 3;
    for (int t = threadIdx.x; t < IC; t += BLOCK) {
        int j = chunk * IC + t;
        sh[t] = make_float4(x2[3*j], x2[3*j+1], x2[3*j+2], wconst);
    }
    __syncthreads();

#pragma unroll
    for (int r = 0; r < RPT; ++r) acc[r] = 0.f;
#pragma unroll 2
    for (int tb = 0; tb < IC; tb += 4) {
        float4 q0 = sh[tb+0], q1 = sh[tb+1], q2 = sh[tb+2], q3 = sh[tb+3];
        float d0[RPT], d1[RPT], d2v[RPT], d3[RPT];
        float dmin = 1e30f;
#pragma unroll
        for (int r = 0; r < RPT; ++r) {
            float dx, dy, dz;
            dx=x[r]-q0.x; dy=y[r]-q0.y; dz=z[r]-q0.z; d0[r]=fmaf(dz,dz,fmaf(dy,dy,dx*dx));
            dx=x[r]-q1.x; dy=y[r]-q1.y; dz=z[r]-q1.z; d1[r]=fmaf(dz,dz,fmaf(dy,dy,dx*dx));
            dx=x[r]-q2.x; dy=y[r]-q2.y; dz=z[r]-q2.z; d2v[r]=fmaf(dz,dz,fmaf(dy,dy,dx*dx));
            dx=x[r]-q3.x; dy=y[r]-q3.y; dz=z[r]-q3.z; d3[r]=fmaf(dz,dz,fmaf(dy,dy,dx*dx));
            dmin = fminf(dmin, fminf(fminf(d0[r], d1[r]), fminf(d2v[r], d3[r])));
        }
        if (__any(dmin < thr)) {
#pragma unroll
            for (int r = 0; r < RPT; ++r) {
                acc[r] += ex2(fmaf(d0[r],  ls, q0.w));
                acc[r] += ex2(fmaf(d1[r],  ls, q1.w));
                acc[r] += ex2(fmaf(d2v[r], ls, q2.w));
                acc[r] += ex2(fmaf(d3[r],  ls, q3.w));
            }
        }
    }
    *(float4*)&P1p[(size_t)chunk * bn + (size_t)bb * n + i0] =
        make_float4(acc[0], acc[1], acc[2], acc[3]);
}

// ---------- pass2 (+fused redL) ----------
__global__ __launch_bounds__(BLOCK, 4)
void emd_pass2(const float* __restrict__ xyzO, const float* __restrict__ xyzS,
               const float* __restrict__ satlIn, float* __restrict__ satlOut,
               const float* __restrict__ aIn, float* __restrict__ aOut,
               const float* __restrict__ P1p, const float* __restrict__ P3a,
               const float* __restrict__ P3b, float* __restrict__ P2p,
               float* __restrict__ cost,
               float ls, float thr, int nO, int nS, int bnS, int bnO,
               int C4, int first)
{
    __shared__ float4 sh[IC];
    __shared__ float red[3][4][IC];
    const int bb = blockIdx.z, chunk = blockIdx.y;

    const int j0 = blockIdx.x * ROWS + threadIdx.x * RPT;
    float x[RPT], y[RPT], z[RPT], acc[RPT];
    load_rows(xyzO + ((size_t)bb * nO + j0) * 3, x, y, z);

    const int t6 = threadIdx.x & 63, g = threadIdx.x >> 6;
    const size_t ri = (size_t)bb * nS + chunk * IC + t6;
    {
        float ps = 0.f, pa = 0.f, pb = 0.f;
        const int c0 = g * C4;
        if (first) {
#pragma unroll 16
            for (int k = 0; k < C4; ++k) ps += P1p[(size_t)(c0 + k) * bnS + ri];
        } else {
#pragma unroll 16
            for (int k = 0; k < C4; ++k) {
                ps += P1p[(size_t)(c0 + k) * bnS + ri];
                pa += P3a[(size_t)(c0 + k) * bnS + ri];
                pb += P3b[(size_t)(c0 + k) * bnS + ri];
            }
        }
        red[0][g][t6] = ps; red[1][g][t6] = pa; red[2][g][t6] = pb;
    }
    __syncthreads();
    if (threadIdx.x < IC) {
        float rs = red[0][0][t6] + red[0][1][t6] + red[0][2][t6] + red[0][3][t6];
        float sl, costv = 0.f;
        if (first) {
            sl = satlIn[ri];
        } else {
            float s1 = red[1][0][t6] + red[1][1][t6] + red[1][2][t6] + red[1][3][t6];
            float s2 = red[2][0][t6] + red[2][1][t6] + red[2][2][t6] + red[2][3][t6];
            float ap = aIn[ri];
            sl = fmaxf(satlIn[ri] - ap * s1, 0.f);
            costv = ap * s2;
        }
        float av = sl / (rs + 1e-9f);
        if (blockIdx.x == 0) {
            satlOut[ri] = sl;
            aOut[ri]    = av;
            if (!first) {
                float cv = wave_reduce_add(costv);
                if (t6 == 0) atomicAdd(&cost[bb], cv);
            }
        }
        const float* xs = xyzS + ((size_t)bb * nS + chunk * IC + t6) * 3;
        sh[t6] = make_float4(xs[0], xs[1], xs[2], lg2(av));
    }
    __syncthreads();

#pragma unroll
    for (int r = 0; r < RPT; ++r) acc[r] = 0.f;
    if (thr < 1e29f) {
#pragma unroll 2
        for (int tb = 0; tb < IC; tb += 4) {
            float4 q0 = sh[tb+0], q1 = sh[tb+1], q2 = sh[tb+2], q3 = sh[tb+3];
            float d0[RPT], d1[RPT], d2v[RPT], d3[RPT];
            float dmin = 1e30f;
#pragma unroll
            for (int r = 0; r < RPT; ++r) {
                float dx, dy, dz;
                dx=x[r]-q0.x; dy=y[r]-q0.y; dz=z[r]-q0.z; d0[r]=fmaf(dz,dz,fmaf(dy,dy,dx*dx));
                dx=x[r]-q1.x; dy=y[r]-q1.y; dz=z[r]-q1.z; d1[r]=fmaf(dz,dz,fmaf(dy,dy,dx*dx));
                dx=x[r]-q2.x; dy=y[r]-q2.y; dz=z[r]-q2.z; d2v[r]=fmaf(dz,dz,fmaf(dy,dy,dx*dx));
                dx=x[r]-q3.x; dy=y[r]-q3.y; dz=z[r]-q3.z; d3[r]=fmaf(dz,dz,fmaf(dy,dy,dx*dx));
                dmin = fminf(dmin, fminf(fminf(d0[r], d1[r]), fminf(d2v[r], d3[r])));
            }
            if (__any(dmin < thr)) {
#pragma unroll
                for (int r = 0; r < RPT; ++r) {
                    acc[r] += ex2(fmaf(d0[r],  ls, q0.w));
                    acc[r] += ex2(fmaf(d1[r],  ls, q1.w));
                    acc[r] += ex2(fmaf(d2v[r], ls, q2.w));
                    acc[r] += ex2(fmaf(d3[r],  ls, q3.w));
                }
            }
        }
    } else {
#pragma unroll 2
        for (int tb = 0; tb < IC; tb += 4) {
            float4 q0 = sh[tb+0], q1 = sh[tb+1], q2 = sh[tb+2], q3 = sh[tb+3];
#pragma unroll
            for (int r = 0; r < RPT; ++r) {
                float dx, dy, dz, d2;
                dx=x[r]-q0.x; dy=y[r]-q0.y; dz=z[r]-q0.z;
                d2=fmaf(dz,dz,fmaf(dy,dy,dx*dx)); acc[r] += ex2(fmaf(d2, ls, q0.w));
                dx=x[r]-q1.x; dy=y[r]-q1.y; dz=z[r]-q1.z;
                d2=fmaf(dz,dz,fmaf(dy,dy,dx*dx)); acc[r] += ex2(fmaf(d2, ls, q1.w));
                dx=x[r]-q2.x; dy=y[r]-q2.y; dz=z[r]-q2.z;
                d2=fmaf(dz,dz,fmaf(dy,dy,dx*dx)); acc[r] += ex2(fmaf(d2, ls, q2.w));
                dx=x[r]-q3.x; dy=y[r]-q3.y; dz=z[r]-q3.z;
                d2=fmaf(dz,dz,fmaf(dy,dy,dx*dx)); acc[r] += ex2(fmaf(d2, ls, q3.w));
            }
        }
    }
    *(float4*)&P2p[(size_t)chunk * bnO + (size_t)bb * nO + j0] =
        make_float4(acc[0], acc[1], acc[2], acc[3]);
}

// ---------- fused (+redR): mode 0 = voted log-folded; mode 1 = t^4 linear
// (exploits level_{L+1} = level_L/4: ONE exp gives both levels); mode 2 = L9
// (lsB = 0: next rowsum = per-chunk sum of sn). ----------
__global__ __launch_bounds__(BLOCK, 4)
void emd_fused(const float* __restrict__ xyz1, const float* __restrict__ xyz2,
               const float* __restrict__ satrIn, float* __restrict__ satrOut,
               const float* __restrict__ P2p,
               float* __restrict__ P3a, float* __restrict__ P3b,
               float* __restrict__ P1p,
               float lsA, float lsB, float thr,
               int n, int m, int bn, int bm, int C4, int mode)
{
    __shared__ float4 sh[IC];   // (qx,qy,qz, r2 or lg2 r2)
    __shared__ float  shB[IC];  // sn or lg2 sn
    __shared__ float  red[4][IC];
    __shared__ float  snsumS;
    const int bb = blockIdx.z, chunk = blockIdx.y;

    const int i0 = blockIdx.x * ROWS + threadIdx.x * RPT;
    float x[RPT], y[RPT], z[RPT];
    load_rows(xyz1 + ((size_t)bb * n + i0) * 3, x, y, z);

    const int t6 = threadIdx.x & 63, g = threadIdx.x >> 6;
    const size_t rj = (size_t)bb * m + chunk * IC + t6;
    {
        float ps = 0.f;
        const int c0 = g * C4;
#pragma unroll 16
        for (int k = 0; k < C4; ++k) ps += P2p[(size_t)(c0 + k) * bm + rj];
        red[g][t6] = ps;
    }
    __syncthreads();
    if (threadIdx.x < IC) {
        float cs  = red[0][t6] + red[1][t6] + red[2][t6] + red[3][t6];
        float sr  = satrIn[rj];
        float cs2 = sr * cs;
        float inv = sr / (cs2 + 1e-9f);
        float r2  = sr * inv;
        float sn  = fmaxf(sr - cs2 * inv, 0.f);
        if (blockIdx.x == 0) satrOut[rj] = sn;
        const float* xs = xyz2 + ((size_t)bb * m + chunk * IC + t6) * 3;
        if (mode == 0) {
            sh[t6]  = make_float4(xs[0], xs[1], xs[2], lg2(r2));
            shB[t6] = lg2(sn);
        } else {
            sh[t6]  = make_float4(xs[0], xs[1], xs[2], r2);
            shB[t6] = sn;
            if (mode == 2) {
                float ss = wave_reduce_add(sn);
                if (t6 == 0) snsumS = ss;
            }
        }
    }
    __syncthreads();

    float s1[RPT], s2[RPT], r1[RPT];
#pragma unroll
    for (int r = 0; r < RPT; ++r) { s1[r] = 0.f; s2[r] = 0.f; r1[r] = 0.f; }

    if (mode == 0) {
#pragma unroll 2
        for (int tb = 0; tb < IC; tb += 4) {
            float4 q0 = sh[tb+0], q1 = sh[tb+1], q2 = sh[tb+2], q3 = sh[tb+3];
            float lb0 = shB[tb+0], lb1 = shB[tb+1], lb2 = shB[tb+2], lb3 = shB[tb+3];
            float d0[RPT], d1[RPT], d2v[RPT], d3[RPT];
            float dmin = 1e30f;
#pragma unroll
            for (int r = 0; r < RPT; ++r) {
                float dx, dy, dz;
                dx=x[r]-q0.x; dy=y[r]-q0.y; dz=z[r]-q0.z; d0[r]=fmaf(dz,dz,fmaf(dy,dy,dx*dx));
                dx=x[r]-q1.x; dy=y[r]-q1.y; dz=z[r]-q1.z; d1[r]=fmaf(dz,dz,fmaf(dy,dy,dx*dx));
                dx=x[r]-q2.x; dy=y[r]-q2.y; dz=z[r]-q2.z; d2v[r]=fmaf(dz,dz,fmaf(dy,dy,dx*dx));
                dx=x[r]-q3.x; dy=y[r]-q3.y; dz=z[r]-q3.z; d3[r]=fmaf(dz,dz,fmaf(dy,dy,dx*dx));
                dmin = fminf(dmin, fminf(fminf(d0[r], d1[r]), fminf(d2v[r], d3[r])));
            }
            if (__any(dmin < thr)) {
#pragma unroll
                for (int r = 0; r < RPT; ++r) {
                    float e;
                    e = ex2(fmaf(d0[r], lsA, q0.w));
                    s1[r] += e; s2[r] = fmaf(e, __builtin_amdgcn_sqrtf(d0[r]), s2[r]);
                    r1[r] += ex2(fmaf(d0[r], lsB, lb0));
                    e = ex2(fmaf(d1[r], lsA, q1.w));
                    s1[r] += e; s2[r] = fmaf(e, __builtin_amdgcn_sqrtf(d1[r]), s2[r]);
                    r1[r] += ex2(fmaf(d1[r], lsB, lb1));
                    e = ex2(fmaf(d2v[r], lsA, q2.w));
                    s1[r] += e; s2[r] = fmaf(e, __builtin_amdgcn_sqrtf(d2v[r]), s2[r]);
                    r1[r] += ex2(fmaf(d2v[r], lsB, lb2));
                    e = ex2(fmaf(d3[r], lsA, q3.w));
                    s1[r] += e; s2[r] = fmaf(e, __builtin_amdgcn_sqrtf(d3[r]), s2[r]);
                    r1[r] += ex2(fmaf(d3[r], lsB, lb3));
                }
            }
        }
    } else if (mode == 1) {
        // t = exp2(lsB*d2); e_A = t^4 (since lsA = 4*lsB exactly); linear weights.
#pragma unroll 2
        for (int tb = 0; tb < IC; tb += 4) {
            float4 q0 = sh[tb+0], q1 = sh[tb+1], q2 = sh[tb+2], q3 = sh[tb+3];
            float lb0 = shB[tb+0], lb1 = shB[tb+1], lb2 = shB[tb+2], lb3 = shB[tb+3];
#pragma unroll
            for (int r = 0; r < RPT; ++r) {
                float dx, dy, dz, d2, t, t2, e3;
                dx=x[r]-q0.x; dy=y[r]-q0.y; dz=z[r]-q0.z;
                d2=fmaf(dz,dz,fmaf(dy,dy,dx*dx));
                t = ex2(d2 * lsB); t2 = t*t; e3 = t2*t2*q0.w;
                s1[r] += e3; s2[r] = fmaf(e3, __builtin_amdgcn_sqrtf(d2), s2[r]);
                r1[r] = fmaf(t, lb0, r1[r]);
                dx=x[r]-q1.x; dy=y[r]-q1.y; dz=z[r]-q1.z;
                d2=fmaf(dz,dz,fmaf(dy,dy,dx*dx));
                t = ex2(d2 * lsB); t2 = t*t; e3 = t2*t2*q1.w;
                s1[r] += e3; s2[r] = fmaf(e3, __builtin_amdgcn_sqrtf(d2), s2[r]);
                r1[r] = fmaf(t, lb1, r1[r]);
                dx=x[r]-q2.x; dy=y[r]-q2.y; dz=z[r]-q2.z;
                d2=fmaf(dz,dz,fmaf(dy,dy,dx*dx));
                t = ex2(d2 * lsB); t2 = t*t; e3 = t2*t2*q2.w;
                s1[r] += e3; s2[r] = fmaf(e3, __builtin_amdgcn_sqrtf(d2), s2[r]);
                r1[r] = fmaf(t, lb2, r1[r]);
                dx=x[r]-q3.x; dy=y[r]-q3.y; dz=z[r]-q3.z;
                d2=fmaf(dz,dz,fmaf(dy,dy,dx*dx));
                t = ex2(d2 * lsB); t2 = t*t; e3 = t2*t2*q3.w;
                s1[r] += e3; s2[r] = fmaf(e3, __builtin_amdgcn_sqrtf(d2), s2[r]);
                r1[r] = fmaf(t, lb3, r1[r]);
            }
        }
    } else {
        // mode 2 (L9): e = exp2(lsA*d2) * r2; r1 = per-chunk sum of sn.
#pragma unroll 2
        for (int tb = 0; tb < IC; tb += 4) {
            float4 q0 = sh[tb+0], q1 = sh[tb+1], q2 = sh[tb+2], q3 = sh[tb+3];
#pragma unroll
            for (int r = 0; r < RPT; ++r) {
                float dx, dy, dz, d2, e;
                dx=x[r]-q0.x; dy=y[r]-q0.y; dz=z[r]-q0.z;
                d2=fmaf(dz,dz,fmaf(dy,dy,dx*dx));
                e = ex2(d2 * lsA) * q0.w;
                s1[r] += e; s2[r] = fmaf(e, __builtin_amdgcn_sqrtf(d2), s2[r]);
                dx=x[r]-q1.x; dy=y[r]-q1.y; dz=z[r]-q1.z;
                d2=fmaf(dz,dz,fmaf(dy,dy,dx*dx));
                e = ex2(d2 * lsA) * q1.w;
                s1[r] += e; s2[r] = fmaf(e, __builtin_amdgcn_sqrtf(d2), s2[r]);
                dx=x[r]-q2.x; dy=y[r]-q2.y; dz=z[r]-q2.z;
                d2=fmaf(dz,dz,fmaf(dy,dy,dx*dx));
                e = ex2(d2 * lsA) * q2.w;
                s1[r] += e; s2[r] = fmaf(e, __builtin_amdgcn_sqrtf(d2), s2[r]);
                dx=x[r]-q3.x; dy=y[r]-q3.y; dz=z[r]-q3.z;
                d2=fmaf(dz,dz,fmaf(dy,dy,dx*dx));
                e = ex2(d2 * lsA) * q3.w;
                s1[r] += e; s2[r] = fmaf(e, __builtin_amdgcn_sqrtf(d2), s2[r]);
            }
        }
    }
    size_t base = (size_t)chunk * bn + (size_t)bb * n + i0;
    if (mode == 2) {
        float sc = snsumS;
#pragma unroll
        for (int r = 0; r < RPT; ++r) r1[r] = sc;
    }
    *(float4*)&P3a[base] = make_float4(s1[0], s1[1], s1[2], s1[3]);
    *(float4*)&P3b[base] = make_float4(s2[0], s2[1], s2[2], s2[3]);
    *(float4*)&P1p[base] = make_float4(r1[0], r1[1], r1[2], r1[3]);
}

// ---------- L10 scalar work: satl/a update, cost(L9), Asum = sum a ----------
__global__ __launch_bounds__(BLOCK)
void emd_redL_last(const float* __restrict__ satl, const float* __restrict__ aIn,
                   float* __restrict__ aOut,
                   const float* __restrict__ P1p, const float* __restrict__ P3a,
                   const float* __restrict__ P3b, float* __restrict__ cost,
                   float* __restrict__ Asum, int C, int bn, int n)
{
    const int idx = blockIdx.x * BLOCK + threadIdx.x;
    float rs = 0.f, s1 = 0.f, s2 = 0.f;
#pragma unroll 16
    for (int c = 0; c < C; ++c) {
        rs += P1p[(size_t)c * bn + idx];
        s1 += P3a[(size_t)c * bn + idx];
        s2 += P3b[(size_t)c * bn + idx];
    }
    float ap = aIn[idx];
    float sl = fmaxf(satl[idx] - ap * s1, 0.f);
    float av = sl / (rs + 1e-9f);
    aOut[idx] = av;
    float cv  = wave_reduce_add(ap * s2);
    float avs = wave_reduce_add(av);
    if ((threadIdx.x & 63) == 0) {
        atomicAdd(&cost[idx / n], cv);
        atomicAdd(&Asum[idx / n], avs);
    }
}

// ---------- last level: s2_i = sum_j r2_j * sqrt(d2); cs = Asum (uniform) ----------
__global__ __launch_bounds__(BLOCK, 4)
void emd_pass3_last(const float* __restrict__ xyz1, const float* __restrict__ xyz2,
                    const float* __restrict__ satrIn, const float* __restrict__ Asum,
                    float* __restrict__ P3b, int n, int m, int bn, int bm)
{
    __shared__ float4 sh[IC];
    const int bb = blockIdx.z, chunk = blockIdx.y;

    const int i0 = blockIdx.x * ROWS + threadIdx.x * RPT;
    float x[RPT], y[RPT], z[RPT], s2[RPT];
    load_rows(xyz1 + ((size_t)bb * n + i0) * 3, x, y, z);

    const float A = Asum[bb];
    for (int t = threadIdx.x; t < IC; t += BLOCK) {
        int j = chunk * IC + t;
        size_t rj = (size_t)bb * m + j;
        float sr  = satrIn[rj];
        float cs2 = sr * A;
        float inv = sr / (cs2 + 1e-9f);
        const float* xs = xyz2 + ((size_t)bb * m + j) * 3;
        sh[t] = make_float4(xs[0], xs[1], xs[2], sr * inv);
    }
    __syncthreads();

#pragma unroll
    for (int r = 0; r < RPT; ++r) s2[r] = 0.f;
#pragma unroll 4
    for (int tb = 0; tb < IC; tb += 4) {
        float4 q0 = sh[tb+0], q1 = sh[tb+1], q2 = sh[tb+2], q3 = sh[tb+3];
#pragma unroll
        for (int r = 0; r < RPT; ++r) {
            float dx, dy, dz, d2;
            dx = x[r]-q0.x; dy = y[r]-q0.y; dz = z[r]-q0.z;
            d2 = fmaf(dz, dz, fmaf(dy, dy, dx*dx));
            s2[r] = fmaf(q0.w, __builtin_amdgcn_sqrtf(d2), s2[r]);
            dx = x[r]-q1.x; dy = y[r]-q1.y; dz = z[r]-q1.z;
            d2 = fmaf(dz, dz, fmaf(dy, dy, dx*dx));
            s2[r] = fmaf(q1.w, __builtin_amdgcn_sqrtf(d2), s2[r]);
            dx = x[r]-q2.x; dy = y[r]-q2.y; dz = z[r]-q2.z;
            d2 = fmaf(dz, dz, fmaf(dy, dy, dx*dx));
            s2[r] = fmaf(q2.w, __builtin_amdgcn_sqrtf(d2), s2[r]);
            dx = x[r]-q3.x; dy = y[r]-q3.y; dz = z[r]-q3.z;
            d2 = fmaf(dz, dz, fmaf(dy, dy, dx*dx));
            s2[r] = fmaf(q3.w, __builtin_amdgcn_sqrtf(d2), s2[r]);
        }
    }
    *(float4*)&P3b[(size_t)chunk * bn + (size_t)bb * n + i0] =
        make_float4(s2[0], s2[1], s2[2], s2[3]);
}

__global__ __launch_bounds__(RBLK)
void emd_final(const float* __restrict__ a, const float* __restrict__ P3b,
               float* __restrict__ cost, int C, int bn, int n)
{
    const int idx = blockIdx.x * RBLK + threadIdx.x;
    float s2 = 0.f;
#pragma unroll 16
    for (int c = 0; c < C; ++c) s2 += P3b[(size_t)c * bn + idx];
    float cv = wave_reduce_add(a[idx] * s2);
    if (threadIdx.x == 0) atomicAdd(&cost[idx / n], cv);
}

extern "C" void kernel_launch(void* const* d_in, const int* in_sizes, int n_in,
                              void* d_out, int out_size, void* d_ws, size_t ws_size,
                              hipStream_t stream)
{
    const float* xyz1 = (const float*)d_in[0];
    const float* xyz2 = (const float*)d_in[1];
    const int b = out_size;                 // 4
    const int n = in_sizes[0] / (3 * b);    // 4096
    const int m = in_sizes[1] / (3 * b);    // 4096
    const int C  = m / IC;                  // j-chunk count
    const int C2 = n / IC;                  // i-chunk count
    const int bn = b * n, bm = b * m;

    float* ws    = (float*)d_ws;
    float* satlA = ws; ws += (size_t)bn;
    float* satlB = ws; ws += (size_t)bn;
    float* satrA = ws; ws += (size_t)bm;
    float* satrB = ws; ws += (size_t)bm;
    float* aA    = ws; ws += (size_t)bn;
    float* aB    = ws; ws += (size_t)bn;
    float* Asum  = ws; ws += 16;
    float* P1p   = ws; ws += (size_t)bn * C;
    float* P2p   = ws; ws += (size_t)bm * C2;
    float* P3a   = ws; ws += (size_t)bn * C;
    float* P3b   = ws; ws += (size_t)bn * C;

    float* out = (float*)d_out;

    const int mx = n > m ? n : m;
    const float fl = (float)(mx / n), fr = (float)(mx / m);
    const float lgfr = log2f(fr);

    emd_init<<<dim3((b * mx + BLOCK - 1) / BLOCK), BLOCK, 0, stream>>>(
        satlA, satrA, out, Asum, fl, fr, b, n, m);

    const double LOG2E = 1.4426950408889634074;
    const double levels[11] = {-65536.0, -16384.0, -4096.0, -1024.0, -256.0,
                               -64.0, -16.0, -4.0, -1.0, -0.25, 0.0};
    float lsv[11], thrP[11], thrF[10];
    for (int k = 0; k < 11; ++k) {
        lsv[k] = (float)(levels[k] * LOG2E);
        thrP[k] = (k <= 3) ? 165.f / fabsf(lsv[k]) : 1e30f;
    }
    for (int k = 0; k < 10; ++k)
        thrF[k] = (k <= 3) ? 165.f / fabsf(lsv[k]) : 1e30f;

    const dim3 g1(n / ROWS, m / IC, b);
    const dim3 g2(m / ROWS, n / IC, b);

    emd_pass1<<<g1, BLOCK, 0, stream>>>(xyz1, xyz2, P1p, lsv[0], lgfr, thrP[0],
                                        n, m, bn);

    float *slI = satlA, *slO = satlB, *aI = aA, *aO = aB;
    float *srI = satrA, *srO = satrB;
    for (int L = 0; L <= 9; ++L) {
        emd_pass2<<<g2, BLOCK, 0, stream>>>(xyz2, xyz1, slI, slO, aI, aO,
                                            P1p, P3a, P3b, P2p, out,
                                            lsv[L], thrP[L], m, n, bn, bm,
                                            C / 4, (L == 0) ? 1 : 0);
        { float* t = slI; slI = slO; slO = t; }
        { float* t = aI;  aI  = aO;  aO  = t; }
        const int mode = (L <= 3) ? 0 : ((L <= 8) ? 1 : 2);
        emd_fused<<<g1, BLOCK, 0, stream>>>(xyz1, xyz2, srI, srO, P2p,
                                            P3a, P3b, P1p,
                                            lsv[L], lsv[L + 1], thrF[L],
                                            n, m, bn, bm, C2 / 4, mode);
        { float* t = srI; srI = srO; srO = t; }
    }
    emd_redL_last<<<dim3(bn / BLOCK), BLOCK, 0, stream>>>(
        slI, aI, aO, P1p, P3a, P3b, out, Asum, C, bn, n);
    emd_pass3_last<<<g1, BLOCK, 0, stream>>>(xyz1, xyz2, srI, Asum, P3b,
                                             n, m, bn, bm);
    emd_final<<<dim3(bn / RBLK), RBLK, 0, stream>>>(aO, P3b, out, C, bn, n);
}